// Round 1
// baseline (164.716 us; speedup 1.0000x reference)
//
#include <hip/hip_runtime.h>
#include <math.h>

// Problem constants
#define DIM 192
#define NT 64        // NUM_TOKENS
#define RD 10
#define BB 32
#define NN 4096
#define LN64 4.1588830833596715f   // ln(64)
#define EPSN 1e-12f

// Workspace layout (floats):
//   knT: [BB][RD][NT]  at offset 0            (32*10*64   = 20480 floats)
//   v:   [BB][NT][DIM] at offset WS_V_OFF     (32*64*192  = 393216 floats)
// total ~1.7 MB — assumed <= ws_size.
#define WS_V_OFF 32768

// ---------------------------------------------------------------------------
// Kernel 1: per-batch k (normalized, stored transposed) and v projections.
// grid = (BB, 6); block = 256. Block (b,y) computes e in [y*32, y*32+32).
// ---------------------------------------------------------------------------
__global__ void ATD_prep_kernel(const float* __restrict__ td,
                                const float* __restrict__ wk_w,
                                const float* __restrict__ wk_b,
                                const float* __restrict__ wv_w,
                                const float* __restrict__ wv_b,
                                float* __restrict__ ws) {
    const int b = blockIdx.x;
    const int y = blockIdx.y;
    const int t = threadIdx.x;

    const float* tdb = td + (size_t)b * (NT * DIM);
    float* knT = ws + (size_t)b * (RD * NT);
    float* v   = ws + WS_V_OFF + (size_t)b * (NT * DIM);

    // ---- v[m][e] = wv_b[e] + sum_c td[m][c] * wv_w[e][c] ----
    const int e  = y * 32 + (t & 31);
    const int tm = t >> 5;                 // 0..7
    const float4* wv4 = reinterpret_cast<const float4*>(wv_w + (size_t)e * DIM);
    for (int j = 0; j < 8; ++j) {
        const int m = tm + 8 * j;
        const float4* td4 = reinterpret_cast<const float4*>(tdb + (size_t)m * DIM);
        float acc = wv_b[e];
        #pragma unroll 8
        for (int c4 = 0; c4 < DIM / 4; ++c4) {
            float4 a = td4[c4];
            float4 w = wv4[c4];
            acc += a.x * w.x + a.y * w.y + a.z * w.z + a.w * w.w;
        }
        v[(size_t)m * DIM + e] = acc;
    }

    // ---- k[m][d] = wk_b[d] + sum_c td[m][c] * wk_w[d][c]; normalize; store knT[d][m] ----
    if (y == 0 && t < NT) {
        const int m = t;
        const float4* td4 = reinterpret_cast<const float4*>(tdb + (size_t)m * DIM);
        float k[RD];
        #pragma unroll
        for (int d = 0; d < RD; ++d) k[d] = wk_b[d];
        for (int c4 = 0; c4 < DIM / 4; ++c4) {
            float4 a = td4[c4];
            #pragma unroll
            for (int d = 0; d < RD; ++d) {
                float4 w = reinterpret_cast<const float4*>(wk_w + (size_t)d * DIM)[c4];
                k[d] += a.x * w.x + a.y * w.y + a.z * w.z + a.w * w.w;
            }
        }
        float ss = 0.f;
        #pragma unroll
        for (int d = 0; d < RD; ++d) ss += k[d] * k[d];
        const float rn = 1.0f / fmaxf(sqrtf(ss), EPSN);
        #pragma unroll
        for (int d = 0; d < RD; ++d) knT[d * NT + m] = k[d] * rn;
    }
}

// ---------------------------------------------------------------------------
// Kernel 2: fused q-projection, l2norm, cosine logits, softmax, attn write,
// PV matmul, out write. Thread-per-row. grid = (NN/256, BB); block = 256.
// LDS: v (48KB) + knT (2.5KB) + wq (7.5KB) = ~58KB -> 2 blocks/CU.
// All hot-loop LDS reads are wave-uniform (broadcast, conflict-free).
// ---------------------------------------------------------------------------
__global__ __launch_bounds__(256, 2) void ATD_main_kernel(
        const float* __restrict__ x,
        const float* __restrict__ wq_w,
        const float* __restrict__ wq_b,
        const float* __restrict__ scale,
        const float* __restrict__ ws,
        float* __restrict__ out,
        float* __restrict__ attn) {
    __shared__ float v_s[NT * DIM];     // 48 KB
    __shared__ float knT_s[RD * NT];    // 2.5 KB
    __shared__ float wq_s[RD * DIM];    // 7.5 KB
    __shared__ float wqb_s[RD];

    const int t = threadIdx.x;
    const int b = blockIdx.y;
    const int r = blockIdx.x * 256 + t;     // row within batch

    // ---- stage v, knT, wq, wq_b into LDS (coalesced float4 copies) ----
    {
        const float4* vsrc = reinterpret_cast<const float4*>(ws + WS_V_OFF + (size_t)b * (NT * DIM));
        float4* vdst = reinterpret_cast<float4*>(v_s);
        #pragma unroll
        for (int i = 0; i < 12; ++i) vdst[t + 256 * i] = vsrc[t + 256 * i];

        const float4* ksrc = reinterpret_cast<const float4*>(ws + (size_t)b * (RD * NT));
        if (t < RD * NT / 4) reinterpret_cast<float4*>(knT_s)[t] = ksrc[t];

        const float4* qsrc = reinterpret_cast<const float4*>(wq_w);
        float4* qdst = reinterpret_cast<float4*>(wq_s);
        qdst[t] = qsrc[t];
        if (t < RD * DIM / 4 - 256) qdst[256 + t] = qsrc[256 + t];

        if (t < RD) wqb_s[t] = wq_b[t];
    }
    __syncthreads();

    const float sc = scale[0];
    const float factor = 1.0f + fminf(fmaxf(sc, 0.0f), 3.0f) * LN64;

    // ---- q projection (streaming x row; wq broadcast from LDS) ----
    float q[RD];
    #pragma unroll
    for (int d = 0; d < RD; ++d) q[d] = wqb_s[d];

    const float4* x4 = reinterpret_cast<const float4*>(x + ((size_t)b * NN + r) * DIM);
    const float4* wq4 = reinterpret_cast<const float4*>(wq_s);
    #pragma unroll 8
    for (int c4 = 0; c4 < DIM / 4; ++c4) {
        float4 xv = x4[c4];
        #pragma unroll
        for (int d = 0; d < RD; ++d) {
            float4 w = wq4[d * (DIM / 4) + c4];
            q[d] += xv.x * w.x + xv.y * w.y + xv.z * w.z + xv.w * w.w;
        }
    }

    // ---- l2 normalize q ----
    {
        float ss = 0.f;
        #pragma unroll
        for (int d = 0; d < RD; ++d) ss += q[d] * q[d];
        const float rn = 1.0f / fmaxf(sqrtf(ss), EPSN);
        #pragma unroll
        for (int d = 0; d < RD; ++d) q[d] *= rn;
    }

    // ---- cosine logits vs all 64 normalized k (broadcast LDS reads) ----
    float l[NT];
    #pragma unroll
    for (int m = 0; m < NT; ++m) l[m] = 0.f;
    #pragma unroll
    for (int d = 0; d < RD; ++d) {
        const float qd = q[d];
        const float4* kn4 = reinterpret_cast<const float4*>(knT_s + d * NT);
        #pragma unroll
        for (int i = 0; i < NT / 4; ++i) {
            float4 kv = kn4[i];
            l[4 * i + 0] += qd * kv.x;
            l[4 * i + 1] += qd * kv.y;
            l[4 * i + 2] += qd * kv.z;
            l[4 * i + 3] += qd * kv.w;
        }
    }

    // ---- scale + softmax over 64 (all in registers, static indexing) ----
    float mx = -1e30f;
    #pragma unroll
    for (int m = 0; m < NT; ++m) { l[m] *= factor; mx = fmaxf(mx, l[m]); }
    float sum = 0.f;
    #pragma unroll
    for (int m = 0; m < NT; ++m) { float p = __expf(l[m] - mx); l[m] = p; sum += p; }
    const float inv = 1.0f / sum;
    #pragma unroll
    for (int m = 0; m < NT; ++m) l[m] *= inv;

    // ---- write attn row (16 x float4) ----
    {
        float4* ap = reinterpret_cast<float4*>(attn + ((size_t)b * NN + r) * NT);
        #pragma unroll
        for (int i = 0; i < NT / 4; ++i)
            ap[i] = make_float4(l[4 * i], l[4 * i + 1], l[4 * i + 2], l[4 * i + 3]);
    }

    // ---- PV: out[e] = sum_m a[m] * v[m][e]  (v broadcast from LDS) ----
    {
        float4* op = reinterpret_cast<float4*>(out + ((size_t)b * NN + r) * DIM);
        const float4* v4 = reinterpret_cast<const float4*>(v_s);
        #pragma unroll 1
        for (int e8 = 0; e8 < DIM; e8 += 8) {
            float ax = 0.f, ay = 0.f, az = 0.f, aw = 0.f;
            float bx = 0.f, by = 0.f, bz = 0.f, bw = 0.f;
            const float4* vb = v4 + (e8 >> 2);
            #pragma unroll
            for (int m = 0; m < NT; ++m) {
                float4 va = vb[m * (DIM / 4)];
                float4 v2 = vb[m * (DIM / 4) + 1];
                const float am = l[m];
                ax += am * va.x; ay += am * va.y; az += am * va.z; aw += am * va.w;
                bx += am * v2.x; by += am * v2.y; bz += am * v2.z; bw += am * v2.w;
            }
            op[(e8 >> 2) + 0] = make_float4(ax, ay, az, aw);
            op[(e8 >> 2) + 1] = make_float4(bx, by, bz, bw);
        }
    }
}

// ---------------------------------------------------------------------------
extern "C" void kernel_launch(void* const* d_in, const int* in_sizes, int n_in,
                              void* d_out, int out_size, void* d_ws, size_t ws_size,
                              hipStream_t stream) {
    const float* x     = (const float*)d_in[0];
    const float* td    = (const float*)d_in[1];
    const float* wq_w  = (const float*)d_in[2];
    const float* wq_b  = (const float*)d_in[3];
    const float* wk_w  = (const float*)d_in[4];
    const float* wk_b  = (const float*)d_in[5];
    const float* wv_w  = (const float*)d_in[6];
    const float* wv_b  = (const float*)d_in[7];
    const float* scale = (const float*)d_in[8];
    // d_in[9] = x_size (unused by the computation)

    float* out  = (float*)d_out;                         // (32,4096,192)
    float* attn = out + (size_t)BB * NN * DIM;           // (32,4096,64)
    float* ws   = (float*)d_ws;

    ATD_prep_kernel<<<dim3(BB, 6), 256, 0, stream>>>(td, wk_w, wk_b, wv_w, wv_b, ws);
    ATD_main_kernel<<<dim3(NN / 256, BB), 256, 0, stream>>>(x, wq_w, wq_b, scale, ws, out, attn);
}